// Round 12
// baseline (192.575 us; speedup 1.0000x reference)
//
#include <hip/hip_runtime.h>
#include <math.h>

// GCNII graph convolution, N=50000, F=256, E=800000, f32 in/out.
// R12: nontemporal hints on pure streams (H0 load + irb store in gather --
//      frees L2 for the random Hs gathers; H load in fillhswt; out store in
//      gemm). hist re-grained: 320 x 256-thread quarter-half blocks (25KB
//      LDS, ~6 blocks/CU) instead of 160 x 1024 (2/CU). Rest = R11.

#define F_DIM 256
#define CHUNK 20000

typedef __attribute__((ext_vector_type(4))) float f32x4;
typedef __attribute__((ext_vector_type(8))) short short8;
typedef __attribute__((ext_vector_type(4))) unsigned short u16x4;

static __device__ __forceinline__ unsigned short f2bf(float f) {
    unsigned int u = __float_as_uint(f);
    u += 0x7fffu + ((u >> 16) & 1u);
    return (unsigned short)(u >> 16);
}
static __device__ __forceinline__ float bf2f(unsigned short u) {
    return __uint_as_float((unsigned int)u << 16);
}

// ---- histogram: block = (chunk c, quarter q, which). u16-packed LDS -------
// word w covers nodes 2w,2w+1; quarter q owns words [q*whq, q*whq+hcount).
// 256 threads, 25KB LDS -> ~6 blocks/CU.

__global__ __launch_bounds__(256) void hist_kernel(
        const int* __restrict__ src, const int* __restrict__ dst,
        unsigned* __restrict__ histS, unsigned* __restrict__ histD,
        unsigned short* __restrict__ lrank, int E, int wpc, int whq) {
    __shared__ unsigned hist[6272];
    int b = blockIdx.x;
    int which = b & 1, q = (b >> 1) & 3, c = b >> 3;
    int tid = threadIdx.x;
    int w0 = q * whq;
    int hcount = wpc - w0 < whq ? wpc - w0 : whq;
    if (hcount <= 0) return;
    int e0 = c * CHUNK;
    int e1 = e0 + CHUNK < E ? e0 + CHUNK : E;
    const int* eptr = which ? dst : src;
    unsigned* outh = which ? histD : histS;

    for (int w = tid; w < hcount; w += 256) hist[w] = 0;
    __syncthreads();
    for (int e = e0 + tid; e < e1; e += 256) {
        int s = eptr[e];
        int wl = (s >> 1) - w0;
        if ((unsigned)wl < (unsigned)hcount) {
            int sh = (s & 1) * 16;
            unsigned old = atomicAdd(&hist[wl], 1u << sh);
            if (!which) lrank[e] = (unsigned short)((old >> sh) & 0xffffu);
        }
    }
    __syncthreads();
    for (int w = tid; w < hcount; w += 256)
        outh[(size_t)c * wpc + w0 + w] = hist[w];
}

// ---- histS/histD pass: cnt, dinv, u16-packed per-chunk bases, blk sums ----

__global__ __launch_bounds__(256) void sumbase_kernel(
        const unsigned* __restrict__ histS, const unsigned* __restrict__ histD,
        int* __restrict__ cnt, float* __restrict__ dinv,
        unsigned* __restrict__ baseL, int* __restrict__ blksum,
        int wpc, int nchunk, int n) {
    int tid = threadIdx.x;
    int w = blockIdx.x * 256 + tid;
    unsigned slo = 0, shi = 0, dlo = 0, dhi = 0;
    if (w < wpc) {
        for (int c = 0; c < nchunk; ++c) {
            unsigned vs = histS[(size_t)c * wpc + w];
            unsigned vd = histD[(size_t)c * wpc + w];
            baseL[(size_t)c * wpc + w] = slo | (shi << 16);
            slo += vs & 0xffffu; shi += vs >> 16;
            dlo += vd & 0xffffu; dhi += vd >> 16;
        }
        int i0 = 2 * w, i1 = 2 * w + 1;
        cnt[i0] = (int)slo;
        dinv[i0] = rsqrtf((float)dlo + 1.0f);
        if (i1 < n) {
            cnt[i1] = (int)shi;
            dinv[i1] = rsqrtf((float)dhi + 1.0f);
        }
    }
    int contrib = 0;
    if (w < wpc) {
        contrib = (int)slo;
        if (2 * w + 1 < n) contrib += (int)shi;
    }
    int lane = tid & 63, wid = tid >> 6;
    int v = contrib;
    for (int off = 32; off > 0; off >>= 1) v += __shfl_down(v, off, 64);
    __shared__ int ws4[4];
    if (lane == 0) ws4[wid] = v;
    __syncthreads();
    if (tid == 0)   blksum[2 * blockIdx.x]     = ws4[0] + ws4[1];
    if (tid == 128) blksum[2 * blockIdx.x + 1] = ws4[2] + ws4[3];
}

// ---- row_ptr: per-block self-scan of blksum + local scan ------------------

__global__ __launch_bounds__(256) void rowptr_kernel(const int* __restrict__ cnt,
                                                     const int* __restrict__ blksum,
                                                     int* __restrict__ row_ptr,
                                                     int n, int nb) {
    int tid = threadIdx.x;
    int lane = tid & 63, w = tid >> 6;
    int bv = (tid < nb) ? blksum[tid] : 0;
    int bs = bv;
    for (int off = 1; off < 64; off <<= 1) {
        int t = __shfl_up(bv, off, 64);
        if (lane >= off) bv += t;
    }
    __shared__ int wsb[4];
    __shared__ int sbo[256];
    if (lane == 63) wsb[w] = bv;
    __syncthreads();
    if (tid == 0) {
        int run = 0;
        for (int k = 0; k < 4; ++k) { int t = wsb[k]; wsb[k] = run; run += t; }
    }
    __syncthreads();
    sbo[tid] = wsb[w] + bv - bs;
    __syncthreads();
    int blockoff = sbo[blockIdx.x];
    int i = blockIdx.x * 256 + tid;
    int s = (i < n) ? cnt[i] : 0;
    int v = s;
    for (int off = 1; off < 64; off <<= 1) {
        int t = __shfl_up(v, off, 64);
        if (lane >= off) v += t;
    }
    __shared__ int ws[4];
    if (lane == 63) ws[w] = v;
    __syncthreads();
    if (tid == 0) {
        int run = 0;
        for (int k = 0; k < 4; ++k) { int t = ws[k]; ws[k] = run; run += t; }
    }
    __syncthreads();
    if (i <= n) row_ptr[i] = blockoff + ws[w] + v - s;
}

// ---- merged: fill (atomic-free CSR col) + Hs build + Wt' build ------------

__global__ __launch_bounds__(256) void fillhswt_kernel(
        const int* __restrict__ src, const int* __restrict__ dst,
        const int* __restrict__ row_ptr, const unsigned* __restrict__ baseL,
        const unsigned short* __restrict__ lrank, int* __restrict__ col,
        const float* __restrict__ H, const float* __restrict__ dinv,
        unsigned short* __restrict__ Hs,
        const float* __restrict__ W, unsigned short* __restrict__ Wt,
        const float* __restrict__ lamda_p, const int* __restrict__ l_p,
        int E, int wpc, int nfill, int total4) {
    int bid = blockIdx.x;
    int tid = threadIdx.x;
    if (bid < nfill) {
        int e = bid * 256 + tid;
        if (e < E) {
            int c = e / CHUNK;
            int s = src[e];
            unsigned word = baseL[(size_t)c * wpc + (s >> 1)];
            unsigned lb = (s & 1) ? (word >> 16) : (word & 0xffffu);
            unsigned pos = (unsigned)row_ptr[s] + lb + lrank[e];
            col[pos] = dst[e];
        }
    } else {
        int i = (bid - nfill) * 256 + tid;   // f32x4 / u16x4 units
        if (i < total4) {
            int row = i >> 6;                 // 64 x f32x4 per row
            float d = dinv[row];
            f32x4 x = __builtin_nontemporal_load((const f32x4*)H + i);
            u16x4 o;
            o[0] = f2bf(x[0] * d); o[1] = f2bf(x[1] * d);
            o[2] = f2bf(x[2] * d); o[3] = f2bf(x[3] * d);
            ((u16x4*)Hs)[i] = o;
        } else {
            int t = i - total4;               // 0..65535 -> Wt' build
            if (t < F_DIM * F_DIM) {
                float beta = logf(lamda_p[0] / (float)l_p[0] + 1.0f);
                int nn = t >> 8, kk = t & 255;
                float v = beta * W[kk * F_DIM + nn];
                if (kk == nn) v += 1.0f - beta;
                Wt[nn * F_DIM + kk] = f2bf(v);
            }
        }
    }
}

// ---- gather: one wave per row, 512B bf16 loads, 8-deep edge unroll --------
// H0 read + irb write are nontemporal (pure streams) -> keep L2 for Hs.

#define ACC(A, h) { A[0] += bf2f(h[0]); A[1] += bf2f(h[1]); \
                    A[2] += bf2f(h[2]); A[3] += bf2f(h[3]); }

__global__ __launch_bounds__(256) void gather_kernel(
        const unsigned short* __restrict__ Hs, const float* __restrict__ H0,
        const int* __restrict__ row_ptr, const int* __restrict__ col,
        const float* __restrict__ dinv, const float* __restrict__ alpha_p,
        unsigned short* __restrict__ irb, int n) {
    int wave = threadIdx.x >> 6;
    int lane = threadIdx.x & 63;
    int row = blockIdx.x * 4 + wave;
    if (row >= n) return;
    float alpha = alpha_p[0];
    const u16x4* Hs4 = (const u16x4*)Hs;

    int beg = row_ptr[row], end = row_ptr[row + 1];
    f32x4 a0 = 0.0f, a1 = 0.0f, a2 = 0.0f, a3 = 0.0f;
    int e = beg;
    for (; e + 8 <= end; e += 8) {             // 8 gathers in flight
        int j0 = col[e+0], j1 = col[e+1], j2 = col[e+2], j3 = col[e+3];
        int j4 = col[e+4], j5 = col[e+5], j6 = col[e+6], j7 = col[e+7];
        u16x4 h0 = Hs4[j0*64+lane], h1 = Hs4[j1*64+lane];
        u16x4 h2 = Hs4[j2*64+lane], h3 = Hs4[j3*64+lane];
        u16x4 h4 = Hs4[j4*64+lane], h5 = Hs4[j5*64+lane];
        u16x4 h6 = Hs4[j6*64+lane], h7 = Hs4[j7*64+lane];
        ACC(a0, h0) ACC(a1, h1) ACC(a2, h2) ACC(a3, h3)
        ACC(a0, h4) ACC(a1, h5) ACC(a2, h6) ACC(a3, h7)
    }
    for (; e + 4 <= end; e += 4) {
        int j0 = col[e+0], j1 = col[e+1], j2 = col[e+2], j3 = col[e+3];
        u16x4 h0 = Hs4[j0*64+lane], h1 = Hs4[j1*64+lane];
        u16x4 h2 = Hs4[j2*64+lane], h3 = Hs4[j3*64+lane];
        ACC(a0, h0) ACC(a1, h1) ACC(a2, h2) ACC(a3, h3)
    }
    for (; e < end; ++e) {
        int j = col[e];
        u16x4 h = Hs4[j*64+lane];
        ACC(a0, h)
    }
    // self loop: H/deg = Hs * dinv  =>  PH = dinv[row] * (sum + Hs_row)
    u16x4 hr = Hs4[row*64+lane];
    ACC(a2, hr)
    f32x4 acc = (a0 + a1) + (a2 + a3);
    float di = dinv[row];
    f32x4 h0v = __builtin_nontemporal_load((const f32x4*)H0 + row * 64 + lane);
    f32x4 init = (1.0f - alpha) * (di * acc) + alpha * h0v;
    u16x4 o;
    o[0] = f2bf(init[0]); o[1] = f2bf(init[1]);
    o[2] = f2bf(init[2]); o[3] = f2bf(init[3]);
    __builtin_nontemporal_store(o, (u16x4*)irb + row * 64 + lane);
}

// ---- GEMM: out = irb @ Wt' (identity pre-folded), pure MFMA + nt store ----
// 4 waves/block; block tile 64 rows x 256 cols; wave w owns cols [w*64,+64).

__global__ __launch_bounds__(256) void gemm_kernel(
        const unsigned short* __restrict__ irb, const unsigned short* __restrict__ Wt,
        float* __restrict__ out, int M) {
    int w = threadIdx.x >> 6;
    int mr = blockIdx.x * 64;
    int nc = w * 64;
    int lane = threadIdx.x & 63;
    int lo = lane & 15, hi = lane >> 4;

    f32x4 acc[4][4] = {};
    for (int kk = 0; kk < 8; ++kk) {
        int kb = kk * 32 + hi * 8;
        short8 a[4], b[4];
        for (int am = 0; am < 4; ++am) {
            int row = mr + am * 16 + lo;
            a[am] = (row < M) ? *(const short8*)(irb + (size_t)row * F_DIM + kb)
                              : (short8)0;
        }
        for (int bn = 0; bn < 4; ++bn) {
            int cb = nc + bn * 16 + lo;
            b[bn] = *(const short8*)(Wt + cb * F_DIM + kb);
        }
        for (int am = 0; am < 4; ++am)
            for (int bn = 0; bn < 4; ++bn)
                acc[am][bn] = __builtin_amdgcn_mfma_f32_16x16x32_bf16(
                    a[am], b[bn], acc[am][bn], 0, 0, 0);
    }

    // C/D layout: col = lane&15, row = (lane>>4)*4 + reg   [m89-verified]
    for (int am = 0; am < 4; ++am) {
        int rbase = mr + am * 16 + hi * 4;
        for (int r = 0; r < 4; ++r) {
            int row = rbase + r;
            if (row >= M) continue;
            for (int bn = 0; bn < 4; ++bn) {
                int c2 = nc + bn * 16 + lo;
                __builtin_nontemporal_store(acc[am][bn][r],
                                            out + (size_t)row * F_DIM + c2);
            }
        }
    }
}

// ---- launch ---------------------------------------------------------------

extern "C" void kernel_launch(void* const* d_in, const int* in_sizes, int n_in,
                              void* d_out, int out_size, void* d_ws, size_t ws_size,
                              hipStream_t stream) {
    const float* H     = (const float*)d_in[0];
    const int*   ei    = (const int*)d_in[1];
    const float* H0    = (const float*)d_in[2];
    const float* W     = (const float*)d_in[3];
    const float* lamda = (const float*)d_in[4];
    const float* alpha = (const float*)d_in[5];
    const int*   lp    = (const int*)d_in[6];

    int n = in_sizes[0] / F_DIM;
    int E = in_sizes[1] / 2;
    const int* src = ei;
    const int* dst = ei + E;
    float* out = (float*)d_out;

    int wpc = (n + 1) / 2;                 // packed words per chunk (25000)
    int whq = (wpc + 3) / 4;               // words per quarter (6250)
    int nchunk = (E + CHUNK - 1) / CHUNK;  // 40
    int nb = (n + 256) / 256;              // scan blocks covering 0..n (196)

    char* ws = (char*)d_ws;
    size_t off = 0;
    auto alloc = [&](size_t bytes) -> void* {
        void* p = ws + off;
        off += (bytes + 255) & ~(size_t)255;
        return p;
    };
    unsigned* histS = (unsigned*)alloc((size_t)nchunk * wpc * 4);   // 4 MB
    unsigned* histD = (unsigned*)alloc((size_t)nchunk * wpc * 4);   // 4 MB
    unsigned* baseL = (unsigned*)alloc((size_t)nchunk * wpc * 4);   // 4 MB (u16 pairs)
    unsigned short* lrank = (unsigned short*)alloc((size_t)E * 2);
    int* cnt     = (int*)alloc((size_t)n * 4);
    int* row_ptr = (int*)alloc(((size_t)n + 1) * 4);
    int* blksum  = (int*)alloc((size_t)(nb + 8) * 4);
    float* dinv  = (float*)alloc((size_t)n * 4);
    int* colb    = (int*)alloc((size_t)E * 4);
    unsigned short* Wt  = (unsigned short*)alloc((size_t)F_DIM * F_DIM * 2);
    unsigned short* Hs  = (unsigned short*)alloc((size_t)n * F_DIM * 2);
    unsigned short* irb = (unsigned short*)alloc(((size_t)n + 64) * F_DIM * 2);

    hist_kernel<<<nchunk * 8, 256, 0, stream>>>(src, dst, histS, histD, lrank,
                                                E, wpc, whq);
    int wgrid = (wpc + 255) / 256;         // 98 blocks -> 196 blksum entries
    sumbase_kernel<<<wgrid, 256, 0, stream>>>(histS, histD, cnt, dinv, baseL,
                                              blksum, wpc, nchunk, n);
    rowptr_kernel<<<nb, 256, 0, stream>>>(cnt, blksum, row_ptr, n, nb);
    int nfill = (E + 255) / 256;
    int total4 = n * 64;
    int nhswt = (total4 + F_DIM * F_DIM + 255) / 256;
    fillhswt_kernel<<<nfill + nhswt, 256, 0, stream>>>(
        src, dst, row_ptr, baseL, lrank, colb,
        H, dinv, Hs, W, Wt, lamda, lp, E, wpc, nfill, total4);
    gather_kernel<<<(n + 3) / 4, 256, 0, stream>>>(Hs, H0, row_ptr, colb, dinv,
                                                   alpha, irb, n);
    int mtiles = (n + 63) / 64;
    gemm_kernel<<<mtiles, 256, 0, stream>>>(irb, Wt, out, n);
}

// Round 13
// 165.745 us; speedup vs baseline: 1.1619x; 1.1619x over previous
//
#include <hip/hip_runtime.h>
#include <math.h>

// GCNII graph convolution, N=50000, F=256, E=800000, f32 in/out.
// R13: R11 pipeline (1024-thread half-block hist, plain fillhswt/gemm) +
//      ONLY the measured R12 win: nontemporal H0 load + irb store in gather
//      (FETCH 214->210MB, 69->66.5us). R12's hist quarter-split (8 scans per
//      edge vs 4) and extra nt hints reverted (+30us regression).

#define F_DIM 256
#define CHUNK 20000

typedef __attribute__((ext_vector_type(4))) float f32x4;
typedef __attribute__((ext_vector_type(8))) short short8;
typedef __attribute__((ext_vector_type(4))) unsigned short u16x4;

static __device__ __forceinline__ unsigned short f2bf(float f) {
    unsigned int u = __float_as_uint(f);
    u += 0x7fffu + ((u >> 16) & 1u);
    return (unsigned short)(u >> 16);
}
static __device__ __forceinline__ float bf2f(unsigned short u) {
    return __uint_as_float((unsigned int)u << 16);
}

// ---- histogram: block = (chunk c, half h, which). u16-packed LDS counts ----

__global__ __launch_bounds__(1024) void hist_kernel(
        const int* __restrict__ src, const int* __restrict__ dst,
        unsigned* __restrict__ histS, unsigned* __restrict__ histD,
        unsigned short* __restrict__ lrank, int E, int wpc, int whalf) {
    __shared__ unsigned hist[12544];
    int b = blockIdx.x;
    int which = b & 1, h = (b >> 1) & 1, c = b >> 2;
    int tid = threadIdx.x;
    int w0 = h * whalf;
    int hcount = h ? (wpc - whalf) : whalf;
    int e0 = c * CHUNK;
    int e1 = e0 + CHUNK < E ? e0 + CHUNK : E;
    const int* eptr = which ? dst : src;
    unsigned* outh = which ? histD : histS;

    for (int w = tid; w < hcount; w += 1024) hist[w] = 0;
    __syncthreads();
    for (int e = e0 + tid; e < e1; e += 1024) {
        int s = eptr[e];
        int wl = (s >> 1) - w0;
        if ((unsigned)wl < (unsigned)hcount) {
            int sh = (s & 1) * 16;
            unsigned old = atomicAdd(&hist[wl], 1u << sh);
            if (!which) lrank[e] = (unsigned short)((old >> sh) & 0xffffu);
        }
    }
    __syncthreads();
    for (int w = tid; w < hcount; w += 1024)
        outh[(size_t)c * wpc + w0 + w] = hist[w];
}

// ---- histS/histD pass: cnt, dinv, u16-packed per-chunk bases, blk sums ----

__global__ __launch_bounds__(256) void sumbase_kernel(
        const unsigned* __restrict__ histS, const unsigned* __restrict__ histD,
        int* __restrict__ cnt, float* __restrict__ dinv,
        unsigned* __restrict__ baseL, int* __restrict__ blksum,
        int wpc, int nchunk, int n) {
    int tid = threadIdx.x;
    int w = blockIdx.x * 256 + tid;
    unsigned slo = 0, shi = 0, dlo = 0, dhi = 0;
    if (w < wpc) {
        for (int c = 0; c < nchunk; ++c) {
            unsigned vs = histS[(size_t)c * wpc + w];
            unsigned vd = histD[(size_t)c * wpc + w];
            baseL[(size_t)c * wpc + w] = slo | (shi << 16);
            slo += vs & 0xffffu; shi += vs >> 16;
            dlo += vd & 0xffffu; dhi += vd >> 16;
        }
        int i0 = 2 * w, i1 = 2 * w + 1;
        cnt[i0] = (int)slo;
        dinv[i0] = rsqrtf((float)dlo + 1.0f);
        if (i1 < n) {
            cnt[i1] = (int)shi;
            dinv[i1] = rsqrtf((float)dhi + 1.0f);
        }
    }
    int contrib = 0;
    if (w < wpc) {
        contrib = (int)slo;
        if (2 * w + 1 < n) contrib += (int)shi;
    }
    int lane = tid & 63, wid = tid >> 6;
    int v = contrib;
    for (int off = 32; off > 0; off >>= 1) v += __shfl_down(v, off, 64);
    __shared__ int ws4[4];
    if (lane == 0) ws4[wid] = v;
    __syncthreads();
    if (tid == 0)   blksum[2 * blockIdx.x]     = ws4[0] + ws4[1];
    if (tid == 128) blksum[2 * blockIdx.x + 1] = ws4[2] + ws4[3];
}

// ---- row_ptr: per-block self-scan of blksum + local scan ------------------

__global__ __launch_bounds__(256) void rowptr_kernel(const int* __restrict__ cnt,
                                                     const int* __restrict__ blksum,
                                                     int* __restrict__ row_ptr,
                                                     int n, int nb) {
    int tid = threadIdx.x;
    int lane = tid & 63, w = tid >> 6;
    int bv = (tid < nb) ? blksum[tid] : 0;
    int bs = bv;
    for (int off = 1; off < 64; off <<= 1) {
        int t = __shfl_up(bv, off, 64);
        if (lane >= off) bv += t;
    }
    __shared__ int wsb[4];
    __shared__ int sbo[256];
    if (lane == 63) wsb[w] = bv;
    __syncthreads();
    if (tid == 0) {
        int run = 0;
        for (int k = 0; k < 4; ++k) { int t = wsb[k]; wsb[k] = run; run += t; }
    }
    __syncthreads();
    sbo[tid] = wsb[w] + bv - bs;
    __syncthreads();
    int blockoff = sbo[blockIdx.x];
    int i = blockIdx.x * 256 + tid;
    int s = (i < n) ? cnt[i] : 0;
    int v = s;
    for (int off = 1; off < 64; off <<= 1) {
        int t = __shfl_up(v, off, 64);
        if (lane >= off) v += t;
    }
    __shared__ int ws[4];
    if (lane == 63) ws[w] = v;
    __syncthreads();
    if (tid == 0) {
        int run = 0;
        for (int k = 0; k < 4; ++k) { int t = ws[k]; ws[k] = run; run += t; }
    }
    __syncthreads();
    if (i <= n) row_ptr[i] = blockoff + ws[w] + v - s;
}

// ---- merged: fill (atomic-free CSR col) + Hs build + Wt' build ------------

__global__ __launch_bounds__(256) void fillhswt_kernel(
        const int* __restrict__ src, const int* __restrict__ dst,
        const int* __restrict__ row_ptr, const unsigned* __restrict__ baseL,
        const unsigned short* __restrict__ lrank, int* __restrict__ col,
        const float* __restrict__ H, const float* __restrict__ dinv,
        unsigned short* __restrict__ Hs,
        const float* __restrict__ W, unsigned short* __restrict__ Wt,
        const float* __restrict__ lamda_p, const int* __restrict__ l_p,
        int E, int wpc, int nfill, int total4) {
    int bid = blockIdx.x;
    int tid = threadIdx.x;
    if (bid < nfill) {
        int e = bid * 256 + tid;
        if (e < E) {
            int c = e / CHUNK;
            int s = src[e];
            unsigned word = baseL[(size_t)c * wpc + (s >> 1)];
            unsigned lb = (s & 1) ? (word >> 16) : (word & 0xffffu);
            unsigned pos = (unsigned)row_ptr[s] + lb + lrank[e];
            col[pos] = dst[e];
        }
    } else {
        int i = (bid - nfill) * 256 + tid;   // f32x4 / u16x4 units
        if (i < total4) {
            int row = i >> 6;                 // 64 x f32x4 per row
            float d = dinv[row];
            f32x4 x = ((const f32x4*)H)[i];
            u16x4 o;
            o[0] = f2bf(x[0] * d); o[1] = f2bf(x[1] * d);
            o[2] = f2bf(x[2] * d); o[3] = f2bf(x[3] * d);
            ((u16x4*)Hs)[i] = o;
        } else {
            int t = i - total4;               // 0..65535 -> Wt' build
            if (t < F_DIM * F_DIM) {
                float beta = logf(lamda_p[0] / (float)l_p[0] + 1.0f);
                int nn = t >> 8, kk = t & 255;
                float v = beta * W[kk * F_DIM + nn];
                if (kk == nn) v += 1.0f - beta;
                Wt[nn * F_DIM + kk] = f2bf(v);
            }
        }
    }
}

// ---- gather: one wave per row, 512B bf16 loads, 8-deep edge unroll --------
// H0 read + irb write are nontemporal (pure streams) -> keep L2 for Hs.

#define ACC(A, h) { A[0] += bf2f(h[0]); A[1] += bf2f(h[1]); \
                    A[2] += bf2f(h[2]); A[3] += bf2f(h[3]); }

__global__ __launch_bounds__(256) void gather_kernel(
        const unsigned short* __restrict__ Hs, const float* __restrict__ H0,
        const int* __restrict__ row_ptr, const int* __restrict__ col,
        const float* __restrict__ dinv, const float* __restrict__ alpha_p,
        unsigned short* __restrict__ irb, int n) {
    int wave = threadIdx.x >> 6;
    int lane = threadIdx.x & 63;
    int row = blockIdx.x * 4 + wave;
    if (row >= n) return;
    float alpha = alpha_p[0];
    const u16x4* Hs4 = (const u16x4*)Hs;

    int beg = row_ptr[row], end = row_ptr[row + 1];
    f32x4 a0 = 0.0f, a1 = 0.0f, a2 = 0.0f, a3 = 0.0f;
    int e = beg;
    for (; e + 8 <= end; e += 8) {             // 8 gathers in flight
        int j0 = col[e+0], j1 = col[e+1], j2 = col[e+2], j3 = col[e+3];
        int j4 = col[e+4], j5 = col[e+5], j6 = col[e+6], j7 = col[e+7];
        u16x4 h0 = Hs4[j0*64+lane], h1 = Hs4[j1*64+lane];
        u16x4 h2 = Hs4[j2*64+lane], h3 = Hs4[j3*64+lane];
        u16x4 h4 = Hs4[j4*64+lane], h5 = Hs4[j5*64+lane];
        u16x4 h6 = Hs4[j6*64+lane], h7 = Hs4[j7*64+lane];
        ACC(a0, h0) ACC(a1, h1) ACC(a2, h2) ACC(a3, h3)
        ACC(a0, h4) ACC(a1, h5) ACC(a2, h6) ACC(a3, h7)
    }
    for (; e + 4 <= end; e += 4) {
        int j0 = col[e+0], j1 = col[e+1], j2 = col[e+2], j3 = col[e+3];
        u16x4 h0 = Hs4[j0*64+lane], h1 = Hs4[j1*64+lane];
        u16x4 h2 = Hs4[j2*64+lane], h3 = Hs4[j3*64+lane];
        ACC(a0, h0) ACC(a1, h1) ACC(a2, h2) ACC(a3, h3)
    }
    for (; e < end; ++e) {
        int j = col[e];
        u16x4 h = Hs4[j*64+lane];
        ACC(a0, h)
    }
    // self loop: H/deg = Hs * dinv  =>  PH = dinv[row] * (sum + Hs_row)
    u16x4 hr = Hs4[row*64+lane];
    ACC(a2, hr)
    f32x4 acc = (a0 + a1) + (a2 + a3);
    float di = dinv[row];
    f32x4 h0v = __builtin_nontemporal_load((const f32x4*)H0 + row * 64 + lane);
    f32x4 init = (1.0f - alpha) * (di * acc) + alpha * h0v;
    u16x4 o;
    o[0] = f2bf(init[0]); o[1] = f2bf(init[1]);
    o[2] = f2bf(init[2]); o[3] = f2bf(init[3]);
    __builtin_nontemporal_store(o, (u16x4*)irb + row * 64 + lane);
}

// ---- GEMM: out = irb @ Wt' (identity pre-folded), pure MFMA + store -------
// 4 waves/block; block tile 64 rows x 256 cols; wave w owns cols [w*64,+64).

__global__ __launch_bounds__(256) void gemm_kernel(
        const unsigned short* __restrict__ irb, const unsigned short* __restrict__ Wt,
        float* __restrict__ out, int M) {
    int w = threadIdx.x >> 6;
    int mr = blockIdx.x * 64;
    int nc = w * 64;
    int lane = threadIdx.x & 63;
    int lo = lane & 15, hi = lane >> 4;

    f32x4 acc[4][4] = {};
    for (int kk = 0; kk < 8; ++kk) {
        int kb = kk * 32 + hi * 8;
        short8 a[4], b[4];
        for (int am = 0; am < 4; ++am) {
            int row = mr + am * 16 + lo;
            a[am] = (row < M) ? *(const short8*)(irb + (size_t)row * F_DIM + kb)
                              : (short8)0;
        }
        for (int bn = 0; bn < 4; ++bn) {
            int cb = nc + bn * 16 + lo;
            b[bn] = *(const short8*)(Wt + cb * F_DIM + kb);
        }
        for (int am = 0; am < 4; ++am)
            for (int bn = 0; bn < 4; ++bn)
                acc[am][bn] = __builtin_amdgcn_mfma_f32_16x16x32_bf16(
                    a[am], b[bn], acc[am][bn], 0, 0, 0);
    }

    // C/D layout: col = lane&15, row = (lane>>4)*4 + reg   [m89-verified]
    for (int am = 0; am < 4; ++am) {
        int rbase = mr + am * 16 + hi * 4;
        for (int r = 0; r < 4; ++r) {
            int row = rbase + r;
            if (row >= M) continue;
            for (int bn = 0; bn < 4; ++bn) {
                int c2 = nc + bn * 16 + lo;
                out[(size_t)row * F_DIM + c2] = acc[am][bn][r];
            }
        }
    }
}

// ---- launch ---------------------------------------------------------------

extern "C" void kernel_launch(void* const* d_in, const int* in_sizes, int n_in,
                              void* d_out, int out_size, void* d_ws, size_t ws_size,
                              hipStream_t stream) {
    const float* H     = (const float*)d_in[0];
    const int*   ei    = (const int*)d_in[1];
    const float* H0    = (const float*)d_in[2];
    const float* W     = (const float*)d_in[3];
    const float* lamda = (const float*)d_in[4];
    const float* alpha = (const float*)d_in[5];
    const int*   lp    = (const int*)d_in[6];

    int n = in_sizes[0] / F_DIM;
    int E = in_sizes[1] / 2;
    const int* src = ei;
    const int* dst = ei + E;
    float* out = (float*)d_out;

    int wpc = (n + 1) / 2;                 // packed words per chunk (25000)
    int whalf = (wpc + 1) / 2;             // words in half 0 (12500)
    int nchunk = (E + CHUNK - 1) / CHUNK;  // 40
    int nb = (n + 256) / 256;              // scan blocks covering 0..n (196)

    char* ws = (char*)d_ws;
    size_t off = 0;
    auto alloc = [&](size_t bytes) -> void* {
        void* p = ws + off;
        off += (bytes + 255) & ~(size_t)255;
        return p;
    };
    unsigned* histS = (unsigned*)alloc((size_t)nchunk * wpc * 4);   // 4 MB
    unsigned* histD = (unsigned*)alloc((size_t)nchunk * wpc * 4);   // 4 MB
    unsigned* baseL = (unsigned*)alloc((size_t)nchunk * wpc * 4);   // 4 MB (u16 pairs)
    unsigned short* lrank = (unsigned short*)alloc((size_t)E * 2);
    int* cnt     = (int*)alloc((size_t)n * 4);
    int* row_ptr = (int*)alloc(((size_t)n + 1) * 4);
    int* blksum  = (int*)alloc((size_t)(nb + 8) * 4);
    float* dinv  = (float*)alloc((size_t)n * 4);
    int* colb    = (int*)alloc((size_t)E * 4);
    unsigned short* Wt  = (unsigned short*)alloc((size_t)F_DIM * F_DIM * 2);
    unsigned short* Hs  = (unsigned short*)alloc((size_t)n * F_DIM * 2);
    unsigned short* irb = (unsigned short*)alloc(((size_t)n + 64) * F_DIM * 2);

    hist_kernel<<<nchunk * 4, 1024, 0, stream>>>(src, dst, histS, histD, lrank,
                                                 E, wpc, whalf);
    int wgrid = (wpc + 255) / 256;         // 98 blocks -> 196 blksum entries
    sumbase_kernel<<<wgrid, 256, 0, stream>>>(histS, histD, cnt, dinv, baseL,
                                              blksum, wpc, nchunk, n);
    rowptr_kernel<<<nb, 256, 0, stream>>>(cnt, blksum, row_ptr, n, nb);
    int nfill = (E + 255) / 256;
    int total4 = n * 64;
    int nhswt = (total4 + F_DIM * F_DIM + 255) / 256;
    fillhswt_kernel<<<nfill + nhswt, 256, 0, stream>>>(
        src, dst, row_ptr, baseL, lrank, colb,
        H, dinv, Hs, W, Wt, lamda, lp, E, wpc, nfill, total4);
    gather_kernel<<<(n + 3) / 4, 256, 0, stream>>>(Hs, H0, row_ptr, colb, dinv,
                                                   alpha, irb, n);
    int mtiles = (n + 63) / 64;
    gemm_kernel<<<mtiles, 256, 0, stream>>>(irb, Wt, out, n);
}